// Round 6
// baseline (28.018 us; speedup 1.0000x reference)
//
#include <hip/hip_runtime.h>
#include <math.h>

#define H_SIDE 14
#define P 196
#define SLAB 38809          // 197*197
#define BIGL (1 << 30)
#define ROWS_PER_BLOCK 16   // one wave64 per row; 1536/16 = 96 blocks, 1 atomic each
#define FXSCALE 68719476736.0   // 2^36 fixed-point scale
#define CNT_SHIFT 50            // completion count packed in bits [50..]

__global__ __launch_bounds__(1024) void blob_fused_kernel(const float* __restrict__ qk,
                                                          unsigned long long* __restrict__ acc,
                                                          float* __restrict__ out,
                                                          int nrows, int nblocks) {
  const int wid  = threadIdx.x >> 6;
  const int lane = threadIdx.x & 63;
  const int row  = blockIdx.x * ROWS_PER_BLOCK + wid;

  // padded 16x16 grid per wave: border = background, interior [1..14]^2
  __shared__ int   lab_s[ROWS_PER_BLOCK][256];
  __shared__ float ps_s [ROWS_PER_BLOCK][256];
  __shared__ float hsum [ROWS_PER_BLOCK];
  int*   lab = lab_s[wid];
  float* ps  = ps_s[wid];

  float h = 0.0f;
  if (row < nrows) {   // exact for 1536 = 96*16; guard kept without early return
    // ---- per-lane owned padded cells: pc = lane + 64k, k=0..3 ----
    int   pc_[4];
    bool  in_[4];
    float x_[4];
    #pragma unroll
    for (int k = 0; k < 4; ++k) {
      const int pc = lane + 64 * k;
      const int pr = pc >> 4, pcc = pc & 15;
      const bool interior = (pr >= 1) & (pr <= H_SIDE) & (pcc >= 1) & (pcc <= H_SIDE);
      const int p = (pr - 1) * H_SIDE + (pcc - 1);   // flat pixel idx 0..195
      pc_[k] = pc; in_[k] = interior;
      x_[k] = interior ? qk[(size_t)row * SLAB + 1 + p] : 0.0f;
    }

    // ---- mean over 196 (wave butterfly, fixed order) ----
    float s = x_[0] + x_[1] + x_[2] + x_[3];
    #pragma unroll
    for (int off = 32; off >= 1; off >>= 1) s += __shfl_xor(s, off);
    const float mean = s * (1.0f / (float)P);

    // ---- mask, xv, init LDS ----
    float v_[4];
    #pragma unroll
    for (int k = 0; k < 4; ++k) {
      const bool msk = in_[k] & (x_[k] > mean);
      v_[k] = msk ? (x_[k] - mean) + 1e-9f : 0.0f;
      lab[pc_[k]] = msk ? pc_[k] : BIGL;   // labels are padded indices (order-preserving)
      ps [pc_[k]] = 0.0f;
    }
    __builtin_amdgcn_wave_barrier();

    // ---- 8-connected min-label propagation + pointer jumping (wave-sync, no barriers) ----
    const int NOFF[8] = {-17, -16, -15, -1, 1, 15, 16, 17};
    for (;;) {
      bool changed = false;
      #pragma unroll
      for (int k = 0; k < 4; ++k) {
        const int pc = pc_[k];
        const int l = lab[pc];
        if (l < BIGL) {                      // masked pixel
          int best = l;
          #pragma unroll
          for (int e = 0; e < 8; ++e) {
            const int nl = lab[pc + NOFF[e]];
            best = best < nl ? best : nl;
          }
          const int jl = lab[best];          // pointer jump (best is a masked cell)
          best = best < jl ? best : jl;
          if (best < l) { lab[pc] = best; changed = true; }
        }
      }
      if (!__any((int)changed)) break;
    }

    // ---- B = sum of masked xv over the row ----
    float b = v_[0] + v_[1] + v_[2] + v_[3];
    #pragma unroll
    for (int off = 32; off >= 1; off >>= 1) b += __shfl_xor(b, off);

    // ---- per-component sums: LDS atomic scatter (wave-lockstep -> deterministic) ----
    #pragma unroll
    for (int k = 0; k < 4; ++k) {
      const int l = lab[pc_[k]];
      if (l < BIGL) atomicAdd(&ps[l], v_[k]);
    }
    __builtin_amdgcn_wave_barrier();

    // ---- entropy at component roots ----
    #pragma unroll
    for (int k = 0; k < 4; ++k) {
      if (lab[pc_[k]] == pc_[k]) {           // root <=> masked && label==self
        const float pn = ps[pc_[k]] / b;
        h += -pn * __logf(pn);
      }
    }
    #pragma unroll
    for (int off = 32; off >= 1; off >>= 1) h += __shfl_xor(h, off);
  }

  // ---- block partial ----
  if (lane == 0) hsum[wid] = h;
  __syncthreads();

  // ---- single packed fixed-point atomic: value in [0,2^50), count in [2^50,...) ----
  if (threadIdx.x == 0) {
    float part = 0.0f;
    #pragma unroll
    for (int w = 0; w < ROWS_PER_BLOCK; ++w) part += hsum[w];
    // H >= 0 always (p_n <= 1). part <= 16*ln(196) ~ 85 -> fx < 2^43; sum < 2^50.
    const unsigned long long fx = (unsigned long long)((double)part * FXSCALE);
    const unsigned long long addend = fx + (1ULL << CNT_SHIFT);
    const unsigned long long old = atomicAdd(acc, addend);   // device-scope RMW
    if ((old >> CNT_SHIFT) == (unsigned long long)(nblocks - 1)) {
      const unsigned long long tot_fx = (old + addend) & ((1ULL << CNT_SHIFT) - 1);
      out[0] = (float)((double)tot_fx * (1.0 / FXSCALE) / (double)nrows);
    }
  }
}

extern "C" void kernel_launch(void* const* d_in, const int* in_sizes, int n_in,
                              void* d_out, int out_size, void* d_ws, size_t ws_size,
                              hipStream_t stream) {
  const float* qk = (const float*)d_in[0];
  float* out = (float*)d_out;
  unsigned long long* acc = (unsigned long long*)d_ws;

  const int nrows = in_sizes[0] / SLAB;                              // 1536
  const int nblk  = (nrows + ROWS_PER_BLOCK - 1) / ROWS_PER_BLOCK;   // 96

  hipMemsetAsync(d_ws, 0, 8, stream);   // zero packed accumulator every call
  blob_fused_kernel<<<nblk, ROWS_PER_BLOCK * 64, 0, stream>>>(qk, acc, out,
                                                              nrows, nblk);
}

// Round 7
// 22.818 us; speedup vs baseline: 1.2279x; 1.2279x over previous
//
#include <hip/hip_runtime.h>
#include <math.h>

#define H_SIDE 14
#define P 196
#define SLAB 38809          // 197*197
#define BIGL (1 << 30)
#define ROWS_PER_BLOCK 4    // one wave64 per row (R2 config — best measured)

__global__ __launch_bounds__(256) void blob_row_kernel(const float* __restrict__ qk,
                                                       float* __restrict__ rowH,
                                                       int nrows) {
  const int wid  = threadIdx.x >> 6;
  const int lane = threadIdx.x & 63;
  const int row  = blockIdx.x * ROWS_PER_BLOCK + wid;
  if (row >= nrows) return;            // no barriers anywhere -> safe

  // padded 16x16 grid per wave: border = background, interior [1..14]^2
  __shared__ int   lab_s[ROWS_PER_BLOCK][256];
  __shared__ float ps_s [ROWS_PER_BLOCK][256];
  int*   lab = lab_s[wid];
  float* ps  = ps_s[wid];

  // ---- per-lane owned padded cells: pc = lane + 64k, k=0..3 ----
  int   pc_[4];
  bool  in_[4];
  float x_[4];
  #pragma unroll
  for (int k = 0; k < 4; ++k) {
    const int pc = lane + 64 * k;
    const int pr = pc >> 4, pcc = pc & 15;
    const bool interior = (pr >= 1) & (pr <= H_SIDE) & (pcc >= 1) & (pcc <= H_SIDE);
    const int p = (pr - 1) * H_SIDE + (pcc - 1);   // flat pixel idx 0..195
    pc_[k] = pc; in_[k] = interior;
    x_[k] = interior ? qk[(size_t)row * SLAB + 1 + p] : 0.0f;
  }

  // ---- mean over 196 (wave butterfly, fixed order) ----
  float s = x_[0] + x_[1] + x_[2] + x_[3];
  #pragma unroll
  for (int off = 32; off >= 1; off >>= 1) s += __shfl_xor(s, off);
  const float mean = s * (1.0f / (float)P);

  // ---- mask, xv, init LDS; own label cached in registers ----
  float v_[4];
  int   l_[4];
  #pragma unroll
  for (int k = 0; k < 4; ++k) {
    const bool msk = in_[k] & (x_[k] > mean);
    v_[k] = msk ? (x_[k] - mean) + 1e-9f : 0.0f;
    l_[k] = msk ? pc_[k] : BIGL;         // labels are padded indices (order-preserving)
    lab[pc_[k]] = l_[k];
    ps [pc_[k]] = 0.0f;
  }
  __builtin_amdgcn_wave_barrier();

  // ---- 8-connected min-label propagation + pointer jumping (wave-sync, no barriers)
  //      own label lives in l_[k]; only the owner writes lab[pc_[k]] -> always coherent
  const int NOFF[8] = {-17, -16, -15, -1, 1, 15, 16, 17};
  for (;;) {
    bool changed = false;
    #pragma unroll
    for (int k = 0; k < 4; ++k) {
      const int l = l_[k];
      if (l < BIGL) {                      // masked pixel
        const int pc = pc_[k];
        int best = l;
        #pragma unroll
        for (int e = 0; e < 8; ++e) {
          const int nl = lab[pc + NOFF[e]];
          best = best < nl ? best : nl;
        }
        const int jl = lab[best];          // pointer jump (best is a masked cell)
        best = best < jl ? best : jl;
        if (best < l) { l_[k] = best; lab[pc] = best; changed = true; }
      }
    }
    if (!__any((int)changed)) break;
  }

  // ---- B = sum of masked xv over the row ----
  float b = v_[0] + v_[1] + v_[2] + v_[3];
  #pragma unroll
  for (int off = 32; off >= 1; off >>= 1) b += __shfl_xor(b, off);

  // ---- per-component sums: LDS atomic scatter (wave-lockstep -> deterministic) ----
  #pragma unroll
  for (int k = 0; k < 4; ++k) {
    if (l_[k] < BIGL) atomicAdd(&ps[l_[k]], v_[k]);
  }
  __builtin_amdgcn_wave_barrier();

  // ---- entropy at component roots ----
  float h = 0.0f;
  #pragma unroll
  for (int k = 0; k < 4; ++k) {
    if (l_[k] == pc_[k]) {                 // root <=> masked && label==self
      const float pn = ps[pc_[k]] / b;
      h += -pn * __logf(pn);
    }
  }
  #pragma unroll
  for (int off = 32; off >= 1; off >>= 1) h += __shfl_xor(h, off);

  if (lane == 0) rowH[row] = h;
}

// single wave, float4 loads, shfl butterfly — no LDS, no barriers
__global__ __launch_bounds__(64) void blob_reduce_kernel(const float* __restrict__ rowH,
                                                         float* __restrict__ out, int n) {
  const int lane = threadIdx.x;
  const float4* r4 = (const float4*)rowH;
  const int n4 = n >> 2;                  // 1536/4 = 384
  float s = 0.0f;
  for (int i = lane; i < n4; i += 64) {   // 6 float4 per lane
    float4 v = r4[i];
    s += v.x + v.y + v.z + v.w;
  }
  #pragma unroll
  for (int off = 32; off >= 1; off >>= 1) s += __shfl_xor(s, off);
  if (lane == 0) out[0] = s / (float)n;
}

extern "C" void kernel_launch(void* const* d_in, const int* in_sizes, int n_in,
                              void* d_out, int out_size, void* d_ws, size_t ws_size,
                              hipStream_t stream) {
  const float* qk = (const float*)d_in[0];
  float* out  = (float*)d_out;
  float* rowH = (float*)d_ws;

  const int nrows = in_sizes[0] / SLAB;   // 1536
  const int nblk  = (nrows + ROWS_PER_BLOCK - 1) / ROWS_PER_BLOCK;

  blob_row_kernel<<<nblk, ROWS_PER_BLOCK * 64, 0, stream>>>(qk, rowH, nrows);
  blob_reduce_kernel<<<1, 64, 0, stream>>>(rowH, out, nrows);
}